// Round 1
// baseline (670.553 us; speedup 1.0000x reference)
//
#include <hip/hip_runtime.h>
#include <hip/hip_fp16.h>

#define B_ 64
#define F_ 4
#define M_ 4096
#define D_ 1024
#define W_ 16      // u64 words per D bits
#define NITER 15

typedef _Float16 f16;
typedef _Float16 f16x8 __attribute__((ext_vector_type(8)));
typedef float f32x4 __attribute__((ext_vector_type(4)));

// ---- device-global scratch (recomputed every call; ~40 MB) ----
__device__ __align__(16) unsigned long long g_cbBits[F_ * M_ * W_];   // 2 MB packed codebooks
__device__ __align__(16) f16 g_cbT[F_ * D_ * M_];                     // 32 MB, [f][d][m] fp16 +-1
__device__ __align__(16) unsigned long long g_inBits[B_ * W_];        // packed input
__device__ __align__(16) unsigned long long g_estBits[B_ * F_ * W_];  // packed estimates
__device__ __align__(16) f16 g_sim[F_ * B_ * M_];                     // 2 MB, [f][b][m] fp16 exact ints
__device__ __align__(16) float g_Cp[4][F_ * B_ * D_];                 // 4 MB K-split partials
__device__ int g_mismatch[16];
__device__ int g_iters;
__device__ int g_conv;

// ---- prep: pack codebooks to bits + build fp16 transpose [f][d][m] ----
__global__ __launch_bounds__(256) void k_prep_cb(const float* __restrict__ cb) {
    int blk = blockIdx.x;           // 4096 = F * 64(mtiles) * 16(dtiles)
    int db = blk & 15;
    int mb = (blk >> 4) & 63;
    int f  = blk >> 10;
    __shared__ float tile[64][65];  // +1 pad: conflict-free transpose
    int tid = threadIdx.x;
    for (int i = tid; i < 4096; i += 256) {
        int mloc = i >> 6, dloc = i & 63;       // one wave == one m-row
        float v = cb[((size_t)(f * M_ + mb * 64 + mloc)) * D_ + db * 64 + dloc];
        tile[mloc][dloc] = v;
        unsigned long long mask = __ballot(v < 0.0f);  // bit=1 <-> -1
        if ((tid & 63) == 0)
            g_cbBits[((size_t)(f * M_ + mb * 64 + mloc)) * W_ + db] = mask;
    }
    __syncthreads();
    for (int i = tid; i < 4096; i += 256) {
        int dloc = i >> 6, mloc = i & 63;
        g_cbT[((size_t)(f * D_ + db * 64 + dloc)) * M_ + mb * 64 + mloc] =
            (f16)tile[mloc][dloc];
    }
}

// ---- prep: pack input + init estimates, zero flags ----
__global__ __launch_bounds__(256) void k_prep_small(const float* __restrict__ inp,
                                                    const float* __restrict__ est0) {
    int blk = blockIdx.x, tid = threadIdx.x;
    if (blk < 64) {
        for (int i = tid; i < D_; i += 256) {
            unsigned long long mask = __ballot(inp[blk * D_ + i] < 0.0f);
            if ((tid & 63) == 0) g_inBits[blk * W_ + (i >> 6)] = mask;
        }
    } else if (blk < 320) {
        int r = blk - 64;  // (b,f) row
        for (int i = tid; i < D_; i += 256) {
            unsigned long long mask = __ballot(est0[(size_t)r * D_ + i] < 0.0f);
            if ((tid & 63) == 0) g_estBits[r * W_ + (i >> 6)] = mask;
        }
    } else {
        if (tid < 16) g_mismatch[tid] = 0;
        if (tid == 16) g_iters = 0;
        if (tid == 17) g_conv = 0;
    }
}

// ---- per-iter phase A: sim[f][b][m] = dot(new_est, cb) via xor+popcount ----
__global__ __launch_bounds__(256) void k_sim(int t) {
    int blk = blockIdx.x;           // 256 = F * 64 m-chunks
    int f = blk & 3, mc = blk >> 2;
    int tid = threadIdx.x;
    if (blk == 0 && tid == 0) {     // fold previous iter's convergence, count this step
        if (t > 0 && g_mismatch[t - 1] == 0) g_conv = 1;
        if (!g_conv) g_iters++;
    }
    __shared__ unsigned long long ne[64][W_];   // new_est bits for all b, this f
    for (int i = tid; i < B_ * W_; i += 256) {
        int b = i >> 4, w = i & 15;
        unsigned long long e0 = g_estBits[(b * 4 + 0) * W_ + w];
        unsigned long long e1 = g_estBits[(b * 4 + 1) * W_ + w];
        unsigned long long e2 = g_estBits[(b * 4 + 2) * W_ + w];
        unsigned long long e3 = g_estBits[(b * 4 + 3) * W_ + w];
        unsigned long long ef = g_estBits[(b * 4 + f) * W_ + w];
        // input * total * est_f  == input * prod_{j!=f} est_j   (XOR domain)
        ne[b][w] = g_inBits[b * W_ + w] ^ e0 ^ e1 ^ e2 ^ e3 ^ ef;
    }
    __syncthreads();
    int m = mc * 64 + (tid & 63);
    int b0 = (tid >> 6) * 16;
    unsigned long long cbw[W_];
    #pragma unroll
    for (int w = 0; w < W_; w++)
        cbw[w] = g_cbBits[((size_t)(f * M_ + m)) * W_ + w];
    for (int b = b0; b < b0 + 16; b++) {
        int p = 0;
        #pragma unroll
        for (int w = 0; w < W_; w++) p += __popcll(cbw[w] ^ ne[b][w]);
        g_sim[((size_t)(f * B_ + b)) * M_ + m] = (f16)(D_ - 2 * p);  // exact in fp16
    }
}

// ---- per-iter phase B: C_partial[kc] = sim(64xK) x cbT(Kx1024) via fp16 MFMA ----
__global__ __launch_bounds__(256) void k_gemm() {
    int blk = blockIdx.x;           // 256 = f(4) x dt(16) x kc(4)
    int f = blk & 3, dt = (blk >> 2) & 15, kc = blk >> 6;
    int tid = threadIdx.x;
    int wv = tid >> 6, lane = tid & 63;
    __shared__ __align__(16) f16 ldsA[64 * 136];  // 64 rows x 128 k, +8 pad
    __shared__ __align__(16) f16 ldsB[64 * 136];
    f32x4 acc[4] = {};
    int k0 = kc * 1024;
    int dbase = dt * 64;
    for (int kb = 0; kb < 8; kb++) {
        int kk = k0 + kb * 128;
        __syncthreads();
        for (int j = 0; j < 4; j++) {
            int i = tid + 256 * j;
            int row = i >> 4, seg = i & 15;
            *(float4*)&ldsA[row * 136 + seg * 8] =
                *(const float4*)&g_sim[((size_t)(f * B_ + row)) * M_ + kk + seg * 8];
            *(float4*)&ldsB[row * 136 + seg * 8] =
                *(const float4*)&g_cbT[((size_t)(f * D_ + dbase + row)) * M_ + kk + seg * 8];
        }
        __syncthreads();
        #pragma unroll
        for (int s = 0; s < 4; s++) {
            int koff = s * 32 + (lane >> 4) * 8;
            f16x8 a = *(f16x8*)&ldsA[(wv * 16 + (lane & 15)) * 136 + koff];
            #pragma unroll
            for (int ct = 0; ct < 4; ct++) {
                f16x8 bf = *(f16x8*)&ldsB[(ct * 16 + (lane & 15)) * 136 + koff];
                acc[ct] = __builtin_amdgcn_mfma_f32_16x16x32_f16(a, bf, acc[ct], 0, 0, 0);
            }
        }
    }
    int col0 = lane & 15, rowoff = (lane >> 4) * 4;
    #pragma unroll
    for (int ct = 0; ct < 4; ct++) {
        int d = dbase + ct * 16 + col0;
        #pragma unroll
        for (int r = 0; r < 4; r++) {
            int b = wv * 16 + rowoff + r;
            g_Cp[kc][((size_t)(f * B_ + b)) * D_ + d] = acc[ct][r];
        }
    }
}

// ---- per-iter phase C: sum partials, sign, update packed est, mismatch flag ----
__global__ __launch_bounds__(256) void k_sign(int t) {
    int blk = blockIdx.x;   // 256 = (b,f)
    int b = blk >> 2, f = blk & 3;
    int tid = threadIdx.x;
    int mism = 0;
    for (int j = 0; j < 4; j++) {
        int d = j * 256 + tid;
        size_t ci = ((size_t)(f * B_ + b)) * D_ + d;
        float v = g_Cp[0][ci] + g_Cp[1][ci] + g_Cp[2][ci] + g_Cp[3][ci]; // exact ints
        unsigned long long mask = __ballot(v < 0.0f);   // sign(0) = +1 -> bit 0
        if ((tid & 63) == 0) {
            size_t ei = (size_t)(b * 4 + f) * W_ + (d >> 6);
            if (g_estBits[ei] != mask) mism = 1;
            g_estBits[ei] = mask;   // unconditional: upd==est once converged
        }
    }
    if (mism) atomicOr(&g_mismatch[t], 1);
}

// ---- final: outcome = argmax|est.cb| (first index on ties), write est/iters/conv ----
__global__ __launch_bounds__(256) void k_final(float* __restrict__ out) {
    int blk = blockIdx.x;   // (b,f)
    int b = blk >> 2, f = blk & 3;
    int tid = threadIdx.x;
    if (blk == 0 && tid == 0) {
        if (g_mismatch[NITER - 1] == 0) g_conv = 1;
        out[256 + 262144] = (float)g_iters;
        out[256 + 262144 + 1] = (float)g_conv;
    }
    // est floats
    for (int j = 0; j < 4; j++) {
        int d = j * 256 + tid;
        unsigned long long w = g_estBits[(size_t)(b * 4 + f) * W_ + (d >> 6)];
        out[256 + ((size_t)(b * 4 + f)) * D_ + d] = ((w >> (d & 63)) & 1) ? -1.0f : 1.0f;
    }
    unsigned long long eb[W_];
    #pragma unroll
    for (int w = 0; w < W_; w++) eb[w] = g_estBits[(size_t)(b * 4 + f) * W_ + w];
    int bestKey = -1;
    for (int j = 0; j < 16; j++) {
        int m = j * 256 + tid;
        int p = 0;
        #pragma unroll
        for (int w = 0; w < W_; w++)
            p += __popcll(eb[w] ^ g_cbBits[((size_t)(f * M_ + m)) * W_ + w]);
        int s = D_ - 2 * p;
        int a = s < 0 ? -s : s;
        int key = (a << 12) | (4095 - m);   // max |sim|, then min m
        if (key > bestKey) bestKey = key;
    }
    __shared__ int red[256];
    red[tid] = bestKey;
    __syncthreads();
    for (int off = 128; off > 0; off >>= 1) {
        if (tid < off) red[tid] = max(red[tid], red[tid + off]);
        __syncthreads();
    }
    if (tid == 0) out[b * 4 + f] = (float)(4095 - (red[0] & 0xFFF));
}

extern "C" void kernel_launch(void* const* d_in, const int* in_sizes, int n_in,
                              void* d_out, int out_size, void* d_ws, size_t ws_size,
                              hipStream_t stream) {
    const float* inp  = (const float*)d_in[0];
    const float* est0 = (const float*)d_in[1];
    const float* cb   = (const float*)d_in[2];
    float* out = (float*)d_out;

    k_prep_cb<<<4096, 256, 0, stream>>>(cb);
    k_prep_small<<<321, 256, 0, stream>>>(inp, est0);
    for (int t = 0; t < NITER; t++) {
        k_sim<<<256, 256, 0, stream>>>(t);
        k_gemm<<<256, 256, 0, stream>>>();
        k_sign<<<256, 256, 0, stream>>>(t);
    }
    k_final<<<256, 256, 0, stream>>>(out);
}

// Round 2
// 408.230 us; speedup vs baseline: 1.6426x; 1.6426x over previous
//
#include <hip/hip_runtime.h>
#include <hip/hip_fp16.h>

#define B_ 64
#define F_ 4
#define M_ 4096
#define D_ 1024
#define W_ 16      // u64 words per D bits
#define CW_ 64     // u64 words per M bits
#define NITER 15

typedef _Float16 f16;
typedef _Float16 f16x8 __attribute__((ext_vector_type(8)));
typedef float f32x4 __attribute__((ext_vector_type(4)));
typedef unsigned int u32;
typedef unsigned long long u64;

// ---- device-global scratch (rebuilt every call) ----
__device__ __align__(16) u64 g_cbBits[F_ * M_ * W_];    // 2 MB: cb packed along d (for final argmax)
__device__ __align__(16) u64 g_colBits[F_ * D_ * CW_];  // 2 MB: cb packed along m (for G)
__device__ __align__(16) f16 g_G[F_ * D_ * D_];         // 8 MB: G = cb^T cb, even ints <=4096, exact fp16
__device__ __align__(16) u64 g_inBits[B_ * W_];
__device__ __align__(16) u64 g_est[2][B_ * F_ * W_];    // ping-pong packed estimates
__device__ int g_mismatch[16];
__device__ int g_iters;
__device__ int g_conv;

// ---- prep: all bit-packings + flag init ----
__global__ __launch_bounds__(256) void k_prep(const float* __restrict__ inp,
                                              const float* __restrict__ est0,
                                              const float* __restrict__ cb) {
    int blk = blockIdx.x, tid = threadIdx.x;
    int wv = tid >> 6, lane = tid & 63;
    if (blk < 256) {                       // colBits: pack along m. blk = f*64 + mw
        int f = blk >> 6, mw = blk & 63;
        const float* base = cb + ((size_t)(f * M_ + mw * 64 + lane)) * D_;
        for (int dq = 0; dq < 64; dq++) {
            int d0 = wv * 256 + dq * 4;
            float4 v = *(const float4*)(base + d0);   // lane streams its own m-row (L1-reused)
            u64 m0 = __ballot(v.x < 0.f);
            u64 m1 = __ballot(v.y < 0.f);
            u64 m2 = __ballot(v.z < 0.f);
            u64 m3 = __ballot(v.w < 0.f);
            if (lane == 0) {
                size_t o = ((size_t)(f * D_ + d0)) * CW_ + mw;
                g_colBits[o] = m0; g_colBits[o + CW_] = m1;
                g_colBits[o + 2 * CW_] = m2; g_colBits[o + 3 * CW_] = m3;
            }
        }
    } else if (blk < 512) {                // cbBits: pack along d. x = f*64 + mc
        int x = blk - 256, f = x >> 6, mc = x & 63;
        for (int it = 0; it < 256; it++) {
            int widx = it * 4 + wv;
            int ml = widx >> 4, w = widx & 15;
            float v = cb[((size_t)(f * M_ + mc * 64 + ml)) * D_ + w * 64 + lane];
            u64 m = __ballot(v < 0.f);
            if (lane == 0) g_cbBits[((size_t)(f * M_ + mc * 64 + ml)) * W_ + w] = m;
        }
    } else if (blk < 576) {                // input pack, b = blk-512
        int b = blk - 512;
        for (int i = tid; i < D_; i += 256) {
            u64 m = __ballot(inp[(size_t)b * D_ + i] < 0.f);
            if (lane == 0) g_inBits[b * W_ + (i >> 6)] = m;
        }
    } else if (blk < 832) {                // est0 pack, row r = b*4+f = blk-576
        int r = blk - 576;
        for (int i = tid; i < D_; i += 256) {
            u64 m = __ballot(est0[(size_t)r * D_ + i] < 0.f);
            if (lane == 0) g_est[0][r * W_ + (i >> 6)] = m;
        }
    } else {
        if (tid < 16) g_mismatch[tid] = 0;
        else if (tid == 16) g_iters = 0;
        else if (tid == 17) g_conv = 0;
    }
}

// ---- G = cb^T cb via xor+popcount on m-packed columns; store fp16 (exact) ----
__global__ __launch_bounds__(256) void k_G() {
    int blk = blockIdx.x;                  // f(4) x t1(16) x t2(16)
    int t2 = blk & 15, t1 = (blk >> 4) & 15, f = blk >> 8;
    __shared__ u64 L1T[64][64];            // transposed tiles: [w][d_loc] (conflict-free reads)
    __shared__ u64 L2T[64][64];
    int tid = threadIdx.x;
    int wv = tid >> 6, lane = tid & 63;
    for (int it = 0; it < 16; it++) {
        int w = it * 4 + wv;
        L1T[w][lane] = g_colBits[((size_t)(f * D_ + t1 * 64 + lane)) * CW_ + w];
        L2T[w][lane] = g_colBits[((size_t)(f * D_ + t2 * 64 + lane)) * CW_ + w];
    }
    __syncthreads();
    int g1 = tid >> 4, g2 = tid & 15;
    int p[4][4] = {};
    for (int w = 0; w < 64; w++) {
        u64 a0 = L1T[w][g1], a1 = L1T[w][g1 + 16], a2 = L1T[w][g1 + 32], a3 = L1T[w][g1 + 48];
        u64 b0 = L2T[w][g2], b1 = L2T[w][g2 + 16], b2 = L2T[w][g2 + 32], b3 = L2T[w][g2 + 48];
        p[0][0] += __popcll(a0 ^ b0); p[0][1] += __popcll(a0 ^ b1);
        p[0][2] += __popcll(a0 ^ b2); p[0][3] += __popcll(a0 ^ b3);
        p[1][0] += __popcll(a1 ^ b0); p[1][1] += __popcll(a1 ^ b1);
        p[1][2] += __popcll(a1 ^ b2); p[1][3] += __popcll(a1 ^ b3);
        p[2][0] += __popcll(a2 ^ b0); p[2][1] += __popcll(a2 ^ b1);
        p[2][2] += __popcll(a2 ^ b2); p[2][3] += __popcll(a2 ^ b3);
        p[3][0] += __popcll(a3 ^ b0); p[3][1] += __popcll(a3 ^ b1);
        p[3][2] += __popcll(a3 ^ b2); p[3][3] += __popcll(a3 ^ b3);
    }
    #pragma unroll
    for (int i = 0; i < 4; i++) {
        int d1 = t1 * 64 + g1 + 16 * i;
        #pragma unroll
        for (int j = 0; j < 4; j++) {
            int d2 = t2 * 64 + g2 + 16 * j;
            g_G[((size_t)(f * D_ + d1)) * D_ + d2] = (f16)(M_ - 2 * p[i][j]);
        }
    }
}

__device__ __forceinline__ u32 pairval(u32 bits, int i) {
    // two halves: bit -> 0x3C00 (+1) or 0xBC00 (-1)
    return 0x3C003C00u | (((bits >> i) & 1u) << 15) | (((bits >> (i + 1)) & 1u) << 31);
}

// ---- one resonator iteration: upd = sign(ne . G), packed-bit update + conv flag ----
__global__ __launch_bounds__(256) void k_iter(int t) {
    int blk = blockIdx.x;                  // 64 = f(4) x dt(16)
    int f = blk & 3, dt = blk >> 2;
    int tid = threadIdx.x;
    int wv = tid >> 6, lane = tid & 63;
    const u64* rb = g_est[t & 1];
    u64* wb = g_est[(t + 1) & 1];
    if (blk == 0 && tid == 0) {            // fold previous iter's convergence
        if (t > 0 && g_mismatch[t - 1] == 0) g_conv = 1;
        if (!g_conv) g_iters++;
    }
    __shared__ u64 ne[64][17];             // +1 pad
    __shared__ __align__(16) f16 ldsA[8192];   // 64 rows x 128 k, XOR-swizzled
    __shared__ __align__(16) f16 ldsB[8192];
    __shared__ unsigned short pack16[64][4];
    for (int idx = tid; idx < 1024; idx += 256) {
        int b = idx >> 4, w = idx & 15;
        u64 e0 = rb[(b * 4 + 0) * W_ + w];
        u64 e1 = rb[(b * 4 + 1) * W_ + w];
        u64 e2 = rb[(b * 4 + 2) * W_ + w];
        u64 e3 = rb[(b * 4 + 3) * W_ + w];
        u64 x = g_inBits[b * W_ + w] ^ e0 ^ e1 ^ e2 ^ e3;
        u64 ef = (f == 0) ? e0 : (f == 1) ? e1 : (f == 2) ? e2 : e3;
        ne[b][w] = x ^ ef;                 // input * prod_{j!=f} est_j in XOR domain
    }
    __syncthreads();
    f32x4 acc[4] = {};
    char* cA = (char*)ldsA;
    char* cB = (char*)ldsB;
    const u32* ne32 = (const u32*)ne;
    const f16* gsrc0 = g_G + ((size_t)(f * D_ + dt * 64)) * D_;
    for (int kb = 0; kb < 8; kb++) {
        if (kb) __syncthreads();
        {   // expand A chunk: bits -> fp16 +-1 into swizzled ldsA (shared by all waves)
            int row = tid & 63, h = tid >> 6;
            u32 bits = ne32[row * 34 + kb * 4 + h];
            int o0 = row * 256 + h * 64;
            int sw = (row & 7) << 4;
            #pragma unroll
            for (int s = 0; s < 4; s++) {
                uint4 u;
                u.x = pairval(bits, s * 8 + 0);
                u.y = pairval(bits, s * 8 + 2);
                u.z = pairval(bits, s * 8 + 4);
                u.w = pairval(bits, s * 8 + 6);
                *(uint4*)(cA + ((o0 + s * 16) ^ sw)) = u;
            }
        }
        {   // stage B chunk (G rows d', k-slice) into swizzled ldsB
            const f16* gsrc = gsrc0 + kb * 128;
            #pragma unroll
            for (int i = 0; i < 4; i++) {
                int o16 = tid + i * 256;
                int row = o16 >> 4, col16 = o16 & 15;
                uint4 v = *(const uint4*)((const char*)gsrc + (size_t)row * 2048 + col16 * 16);
                *(uint4*)(cB + ((row * 256 + col16 * 16) ^ ((row & 7) << 4))) = v;
            }
        }
        __syncthreads();
        #pragma unroll
        for (int s = 0; s < 4; s++) {
            int koff2 = (s * 32 + ((lane >> 4) << 3)) * 2;     // byte offset of k
            int rowB = wv * 16 + (lane & 15);
            f16x8 bf = *(const f16x8*)(cB + ((rowB * 256 + koff2) ^ ((rowB & 7) << 4)));
            #pragma unroll
            for (int rt = 0; rt < 4; rt++) {
                int rowA = rt * 16 + (lane & 15);
                f16x8 af = *(const f16x8*)(cA + ((rowA * 256 + koff2) ^ ((rowA & 7) << 4)));
                acc[rt] = __builtin_amdgcn_mfma_f32_16x16x32_f16(af, bf, acc[rt], 0, 0, 0);
            }
        }
    }
    // epilogue: sign -> bit-pack (cross-wave assembly) -> compare/update/flag
    #pragma unroll
    for (int rt = 0; rt < 4; rt++) {
        #pragma unroll
        for (int j = 0; j < 4; j++) {
            u64 mask = __ballot(acc[rt][j] < 0.0f);
            if ((lane & 15) == 0) {
                int g = lane >> 4;
                pack16[rt * 16 + g * 4 + j][wv] = (unsigned short)(mask >> (g * 16));
            }
        }
    }
    __syncthreads();
    if (tid < 64) {
        int b = tid;
        u64 pk = *(const u64*)&pack16[b][0];
        size_t ei = (size_t)(b * 4 + f) * W_ + dt;
        u64 old = rb[ei];
        wb[ei] = pk;
        u64 mm = __ballot(pk != old);
        if (tid == 0 && mm) atomicOr(&g_mismatch[t], 1);
    }
}

// ---- final: outcome = argmax|est.cb|, write est/iters/conv ----
__global__ __launch_bounds__(256) void k_final(float* __restrict__ out) {
    int blk = blockIdx.x;   // (b,f)
    int b = blk >> 2, f = blk & 3;
    int tid = threadIdx.x;
    const u64* eb_g = g_est[NITER & 1];
    if (blk == 0 && tid == 0) {
        if (g_mismatch[NITER - 1] == 0) g_conv = 1;
        out[256 + 262144] = (float)g_iters;
        out[256 + 262144 + 1] = (float)g_conv;
    }
    for (int j = 0; j < 4; j++) {
        int d = j * 256 + tid;
        u64 w = eb_g[(size_t)(b * 4 + f) * W_ + (d >> 6)];
        out[256 + ((size_t)(b * 4 + f)) * D_ + d] = ((w >> (d & 63)) & 1) ? -1.0f : 1.0f;
    }
    u64 eb[W_];
    #pragma unroll
    for (int w = 0; w < W_; w++) eb[w] = eb_g[(size_t)(b * 4 + f) * W_ + w];
    int bestKey = -1;
    for (int j = 0; j < 16; j++) {
        int m = j * 256 + tid;
        int p = 0;
        #pragma unroll
        for (int w = 0; w < W_; w++)
            p += __popcll(eb[w] ^ g_cbBits[((size_t)(f * M_ + m)) * W_ + w]);
        int s = D_ - 2 * p;
        int a = s < 0 ? -s : s;
        int key = (a << 12) | (4095 - m);   // max |sim|, then min m
        if (key > bestKey) bestKey = key;
    }
    __shared__ int red[256];
    red[tid] = bestKey;
    __syncthreads();
    for (int off = 128; off > 0; off >>= 1) {
        if (tid < off) red[tid] = max(red[tid], red[tid + off]);
        __syncthreads();
    }
    if (tid == 0) out[b * 4 + f] = (float)(4095 - (red[0] & 0xFFF));
}

extern "C" void kernel_launch(void* const* d_in, const int* in_sizes, int n_in,
                              void* d_out, int out_size, void* d_ws, size_t ws_size,
                              hipStream_t stream) {
    (void)d_ws; (void)ws_size;
    const float* inp  = (const float*)d_in[0];
    const float* est0 = (const float*)d_in[1];
    const float* cb   = (const float*)d_in[2];
    float* out = (float*)d_out;

    k_prep<<<833, 256, 0, stream>>>(inp, est0, cb);
    k_G<<<1024, 256, 0, stream>>>();
    for (int t = 0; t < NITER; t++)
        k_iter<<<64, 256, 0, stream>>>(t);
    k_final<<<256, 256, 0, stream>>>(out);
}